// Round 5
// baseline (11.865 us; speedup 1.0000x reference)
//
#include <hip/hip_runtime.h>

constexpr int WIDTH     = 1000;
constexpr int HEIGHT    = 1000;
constexpr int N_PIXELS  = WIDTH * HEIGHT;
constexpr int PATCH     = 5;
constexpr int PATCHES_X = WIDTH / PATCH;      // 200
constexpr int BLOCK     = 64;                 // one wave per block
constexpr int MAXP      = BLOCK / PATCH + 3;  // 15 > max 14 patches per block

// out[c, n] = sum_t sum_d coeff[patch(n), c, t, d] * pix[n, d]^t + bias[patch(n), c]
// Block (bx, py): 5-row band [5*py, 5*py+5) x cols [bx*64, ...). Thread = one
// column of the band: 5 vertical pixels in ONE patch; coef LDS->VGPR once per
// 5 pixels. Horner evaluation: 6 independent 9-fma chains per pixel.
__global__ __launch_bounds__(64) void ts_approx_kernel(
    const float* __restrict__ pix,      // [N, 2]
    const float* __restrict__ coef,     // [NUM_PATCHES, 3, 10, 2] = 60 floats/patch
    const float* __restrict__ bias,     // [NUM_PATCHES, 3]
    float* __restrict__ out)            // [3, N]
{
    __shared__ float scoef[MAXP * 60];
    __shared__ float sbias[MAXP * 3];

    const int tid  = threadIdx.x;
    const int prow = blockIdx.y;                               // patch row, 0..199
    const int c0   = blockIdx.x * BLOCK;
    const int p0   = c0 / PATCH;                               // uniform
    const int pend = min(c0 + BLOCK - 1, WIDTH - 1) / PATCH;   // uniform
    const int np   = pend - p0 + 1;                            // <= 14

    // Stage this block's patch slice (contiguous, coalesced float4).
    const float4* g4 = reinterpret_cast<const float4*>(coef + (size_t)(prow * PATCHES_X + p0) * 60);
    float4* s4 = reinterpret_cast<float4*>(scoef);
    const int nf4 = np * 15;
    for (int j = tid; j < nf4; j += BLOCK) s4[j] = g4[j];
    const float* gb = bias + (size_t)(prow * PATCHES_X + p0) * 3;
    for (int j = tid; j < np * 3; j += BLOCK) sbias[j] = gb[j];
    __syncthreads();

    const int col = c0 + tid;
    if (col >= WIDTH) return;

    const int row0 = prow * PATCH;
    const int pl   = col / PATCH - p0;             // local patch index

    // cf[i] = {c[2i,x], c[2i,y], c[2i+1,x], c[2i+1,y]}; i 0-4 ch0, 5-9 ch1, 10-14 ch2
    float4 cf[15];
    const float4* c4 = reinterpret_cast<const float4*>(scoef + pl * 60);
    #pragma unroll
    for (int i = 0; i < 15; ++i) cf[i] = c4[i];
    const float b0 = sbias[pl * 3 + 0];
    const float b1 = sbias[pl * 3 + 1];
    const float b2 = sbias[pl * 3 + 2];

    const float2* p2 = reinterpret_cast<const float2*>(pix);

    // preload all 5 pixel coords (independent loads issue together)
    float2 p[PATCH];
    #pragma unroll
    for (int r = 0; r < PATCH; ++r) p[r] = p2[(row0 + r) * WIDTH + col];

    #pragma unroll
    for (int r = 0; r < PATCH; ++r) {
        const float x = p[r].x, y = p[r].y;
        const int n = (row0 + r) * WIDTH + col;

        float res[3];
        #pragma unroll
        for (int c = 0; c < 3; ++c) {
            const int b = 5 * c;
            // Horner descending in t: hx = ((c9 x + c8) x + c7) x + ...
            float hx = cf[b + 4].z;                 // c[9, x]
            float hy = cf[b + 4].w;                 // c[9, y]
            hx = fmaf(hx, x, cf[b + 4].x);  hy = fmaf(hy, y, cf[b + 4].y);   // t=8
            hx = fmaf(hx, x, cf[b + 3].z);  hy = fmaf(hy, y, cf[b + 3].w);   // t=7
            hx = fmaf(hx, x, cf[b + 3].x);  hy = fmaf(hy, y, cf[b + 3].y);   // t=6
            hx = fmaf(hx, x, cf[b + 2].z);  hy = fmaf(hy, y, cf[b + 2].w);   // t=5
            hx = fmaf(hx, x, cf[b + 2].x);  hy = fmaf(hy, y, cf[b + 2].y);   // t=4
            hx = fmaf(hx, x, cf[b + 1].z);  hy = fmaf(hy, y, cf[b + 1].w);   // t=3
            hx = fmaf(hx, x, cf[b + 1].x);  hy = fmaf(hy, y, cf[b + 1].y);   // t=2
            hx = fmaf(hx, x, cf[b + 0].z);  hy = fmaf(hy, y, cf[b + 0].w);   // t=1
            hx = fmaf(hx, x, cf[b + 0].x);  hy = fmaf(hy, y, cf[b + 0].y);   // t=0
            res[c] = hx + hy;
        }
        out[0 * N_PIXELS + n] = res[0] + b0;
        out[1 * N_PIXELS + n] = res[1] + b1;
        out[2 * N_PIXELS + n] = res[2] + b2;
    }
}

extern "C" void kernel_launch(void* const* d_in, const int* in_sizes, int n_in,
                              void* d_out, int out_size, void* d_ws, size_t ws_size,
                              hipStream_t stream) {
    const float* pix  = (const float*)d_in[0];
    const float* coef = (const float*)d_in[1];
    const float* bias = (const float*)d_in[2];
    float* out = (float*)d_out;

    dim3 grid((WIDTH + BLOCK - 1) / BLOCK, HEIGHT / PATCH);   // (16, 200)
    ts_approx_kernel<<<grid, BLOCK, 0, stream>>>(pix, coef, bias, out);
}